// Round 12
// baseline (109.589 us; speedup 1.0000x reference)
//
#include <hip/hip_runtime.h>
#include <stdint.h>

#define LL 256
#define DD 256
#define CH 32
#define OT 26        // output tile (per block)
#define HT 32        // halo tile = OT + 6
#define PPH 20       // halfs per halo position in LDS (16 ch + 4 pad)
#define XPAD 272

typedef __attribute__((ext_vector_type(2))) _Float16 f16x2;
typedef __attribute__((ext_vector_type(4))) _Float16 halfx4;
typedef __attribute__((ext_vector_type(8))) _Float16 halfx8;
typedef __attribute__((ext_vector_type(4))) float f32x4;

static __device__ __forceinline__ uint32_t pk16(float a, float b) {
  f16x2 p; p.x = (_Float16)a; p.y = (_Float16)b;   // RTN casts
  return __builtin_bit_cast(uint32_t, p);
}
static __device__ __forceinline__ f16x2 bc2(uint32_t u) { return __builtin_bit_cast(f16x2, u); }
static __device__ __forceinline__ halfx4 bc4(uint2 u) { return __builtin_bit_cast(halfx4, u); }
static __device__ __forceinline__ halfx8 bc8(uint4 u) { return __builtin_bit_cast(halfx8, u); }

// ---------------------------------------------------------------------------
// Kernel P: one-time packing (identical to round 5).
// ---------------------------------------------------------------------------
__global__ void bepler_pack(const float* __restrict__ x, const float* __restrict__ W1,
                            const float* __restrict__ W2, _Float16* __restrict__ xf,
                            _Float16* __restrict__ w1p, uint2* __restrict__ w2b) {
  const int gid = blockIdx.x * 256 + threadIdx.x;
  if (blockIdx.x < 256) {
    const float4 f0 = ((const float4*)x)[gid * 2];
    const float4 f1 = ((const float4*)x)[gid * 2 + 1];
    uint4 v;
    v.x = pk16(f0.x, f0.y); v.y = pk16(f0.z, f0.w);
    v.z = pk16(f1.x, f1.y); v.w = pk16(f1.z, f1.w);
    ((uint4*)xf)[gid] = v;
  } else if (blockIdx.x < 320) {
    const int idx = gid - 65536;           // 0..16383
    const int t  = idx & 7;
    const int l  = (idx >> 3) & 63;
    const int hM = (idx >> 9) & 1;
    const int s  = idx >> 10;
    const int g  = (l >> 4) & 3;
    const int d  = 32 * (s >> 1) + 8 * g + 4 * (s & 1) + 2 * ((t >> 2) & 1) + (t & 1);
    const int ko = (t & 2) ? (DD + d) : d;
    w1p[idx] = (_Float16)W1[ko * CH + 16 * hM + (l & 15)];
  } else {
    for (int k = threadIdx.x; k < 2 * 7 * 64; k += 256) {
      const int l  = k & 63;
      const int kk = (k >> 6) % 7;
      const int ph = k / 448;
      const int di = l & 15;
      const int G  = l >> 4;
      uint2 v = make_uint2(0u, 0u);
      if (di < 7) {
        const float* ws = W2 + ((di * 7) + kk) * 32 + ph * 16 + G * 4;
        v.x = pk16(ws[0], ws[1]);
        v.y = pk16(ws[2], ws[3]);
      }
      w2b[k] = v;
    }
  }
}

// ---------------------------------------------------------------------------
// FUSED kernel, I$-footprint restructure (round-5 math bitwise):
//  - OUTER hM (channel-half) LOOP, #pragma unroll 1: per pass load half the
//    W1 frags (afh[16], 64 VGPR), A-phase for 16 ch with RUNTIME ip loop
//    (accH1p register array eliminated -> ip no longer needs unrolling),
//    write h half to hts, then conv those 16 channels.
//  - Kernel text ~8-10K instr (~75 KB, streams through I$ every pass) ->
//    ~1.5K instr (~12 KB, I$-resident). Per-channel MFMA chains, h f16
//    values, and a2 accumulation order identical to round 5.
//  - Barriers: stage|bar| {A->bar->conv->bar} x2 |scatter|bar|reduce.
//    Trailing per-pass bar separates conv reads from next A hts writes and
//    A-phase xi reads from the rb(ubuf-alias) scatter write.
// Grid (10,10,8) = round 5 exactly (proven fastest ordering).
// ---------------------------------------------------------------------------
__global__ __launch_bounds__(256, 2) void bepler_fused(
    const _Float16* __restrict__ xf, const int* __restrict__ plen,
    const uint4* __restrict__ w1p4, const float* __restrict__ b1,
    const uint2* __restrict__ w2b, const float* __restrict__ b2,
    float* __restrict__ out)
{
  __shared__ _Float16 hts[HT * HT * PPH + 8 * PPH];       // 41,280 B (+pad)
  __shared__ __align__(16) char ubuf[2 * 32 * XPAD * 2];  // 34,816 B
  _Float16* xi = (_Float16*)ubuf;
  _Float16* xj = xi + 32 * XPAD;
  float (*rb)[2][32][32] = (float (*)[2][32][32])ubuf;    // 32,768 B alias

  const int tid  = threadIdx.x;
  const int lane = tid & 63;
  const int wv   = tid >> 6;
  const int b    = blockIdx.z;
  const int oi0  = blockIdx.y * OT;
  const int oj0  = blockIdx.x * OT;
  const int hi0  = oi0 - 3, hj0 = oj0 - 3;
  const int len  = plen[b];
  const float bias = b2[0];

  if (oi0 >= len || oj0 >= len) {        // whole out tile masked -> zeros
    for (int p = tid; p < OT * OT; p += 256) {
      const int gi = oi0 + p / OT, gj = oj0 + p % OT;
      if (gi < LL && gj < LL) out[(size_t)(b * LL + gi) * LL + gj] = 0.f;
    }
    return;
  }

  const int g   = lane >> 4;
  const int m16 = lane & 15;

  // Stage x halo rows (clamped; invalid rows masked to 0 in h below)
  const _Float16* xfb = xf + (size_t)b * LL * DD;
  for (int idx = tid; idx < 1024; idx += 256) {
    const int r = idx >> 5, cg = idx & 31;
    int ri = hi0 + r; ri = ri < 0 ? 0 : (ri > LL - 1 ? LL - 1 : ri);
    int rj = hj0 + r; rj = rj < 0 ? 0 : (rj > LL - 1 ? LL - 1 : rj);
    ((uint4*)(xi + r * XPAD))[cg] = ((const uint4*)(xfb + ri * DD))[cg];
    ((uint4*)(xj + r * XPAD))[cg] = ((const uint4*)(xfb + rj * DD))[cg];
  }
  __syncthreads();

  float a2[2][32];
#pragma unroll
  for (int js = 0; js < 2; ++js)
#pragma unroll
    for (int s = 0; s < 32; ++s) a2[js][s] = 0.f;

#pragma unroll 1
  for (int hM = 0; hM < 2; ++hM) {       // channel-half pass (NOT unrolled)
    // W1 A-frag half (64 VGPR) + bias half, L2-hot
    uint4 afh[16];
#pragma unroll
    for (int s = 0; s < 16; ++s) afh[s] = w1p4[(s * 2 + hM) * 64 + lane];
    float b1h[4];
#pragma unroll
    for (int r = 0; r < 4; ++r) b1h[r] = b1[hM * 16 + g * 4 + r];

    // ---- A-phase: h halo tile (16 ch) -> hts ----
#pragma unroll 1
    for (int ip = 0; ip < 4; ++ip) {     // runtime loop (no reg-array idx)
      const int r0 = wv * 8 + 2 * ip;
      const int r1 = r0 + 1;
      f32x4 acc[2][2];                   // [rr][jg]
#pragma unroll
      for (int rr = 0; rr < 2; ++rr)
#pragma unroll
        for (int jg = 0; jg < 2; ++jg)
          acc[rr][jg] = (f32x4){0.f, 0.f, 0.f, 0.f};

#pragma unroll
      for (int m = 0; m < 8; ++m) {
        const int doff = 32 * m + 8 * g;
        const uint4 ua0 = *(const uint4*)(xi + r0 * XPAD + doff);
        const uint4 ua1 = *(const uint4*)(xi + r1 * XPAD + doff);
#pragma unroll
        for (int jg = 0; jg < 2; ++jg) {
          const uint4 uc = *(const uint4*)(xj + (jg * 16 + m16) * XPAD + doff);
          const f16x2 c0 = bc2(uc.x), c1 = bc2(uc.y), c2 = bc2(uc.z), c3 = bc2(uc.w);
#pragma unroll
          for (int rr = 0; rr < 2; ++rr) {
            const uint4 ua = rr ? ua1 : ua0;
            const f16x2 a0 = bc2(ua.x), a1 = bc2(ua.y), a2v = bc2(ua.z), a3 = bc2(ua.w);
            const f16x2 p0 = a0 * c0, p1 = a1 * c1, p2 = a2v * c2, p3 = a3 * c3;
            const uint32_t s0 = __builtin_bit_cast(uint32_t, a0 - c0) & 0x7FFF7FFFu;
            const uint32_t s1 = __builtin_bit_cast(uint32_t, a1 - c1) & 0x7FFF7FFFu;
            const uint32_t s2 = __builtin_bit_cast(uint32_t, a2v - c2) & 0x7FFF7FFFu;
            const uint32_t s3 = __builtin_bit_cast(uint32_t, a3 - c3) & 0x7FFF7FFFu;
            uint4 be, bo;
            be.x = __builtin_bit_cast(uint32_t, p0); be.y = s0;
            be.z = __builtin_bit_cast(uint32_t, p1); be.w = s1;
            bo.x = __builtin_bit_cast(uint32_t, p2); bo.y = s2;
            bo.z = __builtin_bit_cast(uint32_t, p3); bo.w = s3;
            acc[rr][jg] = __builtin_amdgcn_mfma_f32_16x16x32_f16(bc8(afh[2 * m]),     bc8(be), acc[rr][jg], 0, 0, 0);
            acc[rr][jg] = __builtin_amdgcn_mfma_f32_16x16x32_f16(bc8(afh[2 * m + 1]), bc8(bo), acc[rr][jg], 0, 0, 0);
          }
        }
      }

      // relu+bias+mask -> hts (this channel half)
#pragma unroll
      for (int rr = 0; rr < 2; ++rr) {
        const int rloc = rr ? r1 : r0;
        const int gi = hi0 + rloc;
#pragma unroll
        for (int jg = 0; jg < 2; ++jg) {
          const int jl = jg * 16 + m16;
          const int gj = hj0 + jl;
          const float msk = (gi >= 0 && gi < len && gj >= 0 && gj < len) ? 1.f : 0.f;
          const f32x4 a = acc[rr][jg];
          uint2 st;
          st.x = pk16(fmaxf(a[0] + b1h[0], 0.f) * msk, fmaxf(a[1] + b1h[1], 0.f) * msk);
          st.y = pk16(fmaxf(a[2] + b1h[2], 0.f) * msk, fmaxf(a[3] + b1h[3], 0.f) * msk);
          *(uint2*)(hts + (rloc * HT + jl) * PPH + g * 4) = st;
        }
      }
    }
    __syncthreads();                     // hts complete for this half

    // ---- conv for this channel half ----
    {
      uint2 wf[7];
#pragma unroll
      for (int kk = 0; kk < 7; ++kk) wf[kk] = w2b[hM * 448 + kk * 64 + lane];
#pragma unroll
      for (int t = 0; t < 8; ++t) {      // unrolled: a2 index must be static
        const int r = wv + 4 * t;        // halo row 0..31
#pragma unroll
        for (int js = 0; js < 2; ++js) {
          const _Float16* base = hts + (r * HT + js * 16 + m16) * PPH + g * 4;
          f32x4 c = (f32x4){0.f, 0.f, 0.f, 0.f};
#pragma unroll
          for (int kk = 0; kk < 7; ++kk)
            c = __builtin_amdgcn_mfma_f32_16x16x16f16(bc4(wf[kk]), bc4(*(const uint2*)(base + kk * PPH)), c, 0, 0, 0);
#pragma unroll
          for (int reg = 0; reg < 4; ++reg)
            a2[js][4 * t - reg + 3] += c[reg];
        }
      }
    }
    __syncthreads();                     // before next pass overwrites hts
  }

  // ---- scatter to reduce buffer (aliases dead x staging) ----
  if (g < 2) {
#pragma unroll
    for (int s = 0; s < 32; ++s) {
      rb[wv][g][s][m16]      = a2[0][s];
      rb[wv][g][s][16 + m16] = a2[1][s];
    }
  }
  __syncthreads();

  // ---- reduce + store ----
  for (int p = tid; p < OT * OT; p += 256) {
    const int oi = p / OT, oj = p - (p / OT) * OT;
    float sum = 0.f;
#pragma unroll
    for (int ww = 0; ww < 4; ++ww)
#pragma unroll
      for (int gg = 0; gg < 2; ++gg) {
        const int s = oi - ww + 4 * gg + 3;
        if (s < 32) sum += rb[ww][gg][s][oj];
      }
    const int gi = oi0 + oi, gj = oj0 + oj;
    if (gi < LL && gj < LL)
      out[(size_t)(b * LL + gi) * LL + gj] = (gi < len && gj < len) ? sum + bias : 0.f;
  }
}

extern "C" void kernel_launch(void* const* d_in, const int* in_sizes, int n_in,
                              void* d_out, int out_size, void* d_ws, size_t ws_size,
                              hipStream_t stream) {
  const float* x   = (const float*)d_in[0];
  const int*   pl  = (const int*)d_in[1];
  const float* W1  = (const float*)d_in[2];
  const float* b1  = (const float*)d_in[3];
  const float* W2  = (const float*)d_in[4];
  const float* b2  = (const float*)d_in[5];
  float* out = (float*)d_out;

  _Float16* w1p = (_Float16*)d_ws;                      // 32,768 B
  uint2*    w2b = (uint2*)((char*)d_ws + 32768);        // 7,168 B
  _Float16* xf  = (_Float16*)((char*)d_ws + 65536);     // 1,048,576 B

  bepler_pack<<<dim3(321), dim3(256), 0, stream>>>(x, W1, W2, xf, w1p, w2b);
  dim3 gF(10, 10, 8);  // (j-tile/26, i-tile/26, b) — round-5 proven order
  bepler_fused<<<gF, dim3(256), 0, stream>>>(xf, pl, (const uint4*)w1p, b1, w2b, b2, out);
}

// Round 13
// 100.930 us; speedup vs baseline: 1.0858x; 1.0858x over previous
//
#include <hip/hip_runtime.h>
#include <stdint.h>

#define LL 256
#define DD 256
#define CH 32
#define OT 26        // output tile (per block)
#define HT 32        // halo tile = OT + 6
#define PPH 20       // halfs per halo position in LDS (16 ch + 4 pad)
#define XPAD 272

typedef __attribute__((ext_vector_type(2))) _Float16 f16x2;
typedef __attribute__((ext_vector_type(4))) _Float16 halfx4;
typedef __attribute__((ext_vector_type(8))) _Float16 halfx8;
typedef __attribute__((ext_vector_type(4))) float f32x4;

static __device__ __forceinline__ uint32_t pk16(float a, float b) {
  f16x2 p; p.x = (_Float16)a; p.y = (_Float16)b;   // RTN casts
  return __builtin_bit_cast(uint32_t, p);
}
static __device__ __forceinline__ f16x2 bc2(uint32_t u) { return __builtin_bit_cast(f16x2, u); }
static __device__ __forceinline__ halfx4 bc4(uint2 u) { return __builtin_bit_cast(halfx4, u); }
static __device__ __forceinline__ halfx8 bc8(uint4 u) { return __builtin_bit_cast(halfx8, u); }

// ---------------------------------------------------------------------------
// Kernel P: one-time packing (round-5 verbatim).
// ---------------------------------------------------------------------------
__global__ void bepler_pack(const float* __restrict__ x, const float* __restrict__ W1,
                            const float* __restrict__ W2, _Float16* __restrict__ xf,
                            _Float16* __restrict__ w1p, uint2* __restrict__ w2b) {
  const int gid = blockIdx.x * 256 + threadIdx.x;
  if (blockIdx.x < 256) {
    const float4 f0 = ((const float4*)x)[gid * 2];
    const float4 f1 = ((const float4*)x)[gid * 2 + 1];
    uint4 v;
    v.x = pk16(f0.x, f0.y); v.y = pk16(f0.z, f0.w);
    v.z = pk16(f1.x, f1.y); v.w = pk16(f1.z, f1.w);
    ((uint4*)xf)[gid] = v;
  } else if (blockIdx.x < 320) {
    const int idx = gid - 65536;           // 0..16383
    const int t  = idx & 7;
    const int l  = (idx >> 3) & 63;
    const int hM = (idx >> 9) & 1;
    const int s  = idx >> 10;
    const int g  = (l >> 4) & 3;
    const int d  = 32 * (s >> 1) + 8 * g + 4 * (s & 1) + 2 * ((t >> 2) & 1) + (t & 1);
    const int ko = (t & 2) ? (DD + d) : d;
    w1p[idx] = (_Float16)W1[ko * CH + 16 * hM + (l & 15)];
  } else {
    for (int k = threadIdx.x; k < 2 * 7 * 64; k += 256) {
      const int l  = k & 63;
      const int kk = (k >> 6) % 7;
      const int ph = k / 448;
      const int di = l & 15;
      const int G  = l >> 4;
      uint2 v = make_uint2(0u, 0u);
      if (di < 7) {
        const float* ws = W2 + ((di * 7) + kk) * 32 + ph * 16 + G * 4;
        v.x = pk16(ws[0], ws[1]);
        v.y = pk16(ws[2], ws[3]);
      }
      w2b[k] = v;
    }
  }
}

// ---------------------------------------------------------------------------
// FUSED kernel: round-5 configuration VERBATIM — best verified (100.8 us,
// reproduced 102.0). Six perturbations (512-thread split, setprio, b-fastest
// grid, shell order, I$ shrink) all regressed or raced; this is the floor.
// ---------------------------------------------------------------------------
__global__ __launch_bounds__(256, 2) void bepler_fused(
    const _Float16* __restrict__ xf, const int* __restrict__ plen,
    const uint4* __restrict__ w1p4, const float* __restrict__ b1,
    const uint2* __restrict__ w2b, const float* __restrict__ b2,
    float* __restrict__ out)
{
  __shared__ _Float16 hts[HT * HT * PPH + 8 * PPH];       // 41,280 B (+pad)
  __shared__ __align__(16) char ubuf[2 * 32 * XPAD * 2];  // 34,816 B
  _Float16* xi = (_Float16*)ubuf;
  _Float16* xj = xi + 32 * XPAD;
  float (*rb)[2][32][32] = (float (*)[2][32][32])ubuf;    // 32,768 B alias

  const int tid  = threadIdx.x;
  const int lane = tid & 63;
  const int wv   = tid >> 6;
  const int b    = blockIdx.z;
  const int oi0  = blockIdx.y * OT;
  const int oj0  = blockIdx.x * OT;
  const int hi0  = oi0 - 3, hj0 = oj0 - 3;
  const int len  = plen[b];
  const float bias = b2[0];

  if (oi0 >= len || oj0 >= len) {        // whole out tile masked -> zeros
    for (int p = tid; p < OT * OT; p += 256) {
      const int gi = oi0 + p / OT, gj = oj0 + p % OT;
      if (gi < LL && gj < LL) out[(size_t)(b * LL + gi) * LL + gj] = 0.f;
    }
    return;
  }

  const int g   = lane >> 4;
  const int m16 = lane & 15;

  // W1 A-frags from prepacked global (L2-hot): 128 VGPR
  uint4 af[16][2];
#pragma unroll
  for (int s = 0; s < 16; ++s) {
#pragma unroll
    for (int hM = 0; hM < 2; ++hM)
      af[s][hM] = w1p4[(s * 2 + hM) * 64 + lane];
  }

  // Stage x halo rows (clamped; invalid rows masked to 0 in h below)
  const _Float16* xfb = xf + (size_t)b * LL * DD;
  for (int idx = tid; idx < 1024; idx += 256) {
    const int r = idx >> 5, cg = idx & 31;
    int ri = hi0 + r; ri = ri < 0 ? 0 : (ri > LL - 1 ? LL - 1 : ri);
    int rj = hj0 + r; rj = rj < 0 ? 0 : (rj > LL - 1 ? LL - 1 : rj);
    ((uint4*)(xi + r * XPAD))[cg] = ((const uint4*)(xfb + ri * DD))[cg];
    ((uint4*)(xj + r * XPAD))[cg] = ((const uint4*)(xfb + rj * DD))[cg];
  }

  float b1v[2][4];
#pragma unroll
  for (int r = 0; r < 4; ++r) {
    b1v[0][r] = b1[g * 4 + r];
    b1v[1][r] = b1[16 + g * 4 + r];
  }
  __syncthreads();

  // ---- A-phase: h halo tile -> LDS (phase-0 ch) + regs (phase-1 ch) ----
  uint2 accH1p[16];                      // [ip*4 + jg*2 + rr], static idx
#pragma unroll
  for (int ip = 0; ip < 4; ++ip) {
    const int r0 = wv * 8 + 2 * ip;
    const int r1 = r0 + 1;
    f32x4 acc[2][2][2];                  // [rr][jg][hM]
#pragma unroll
    for (int rr = 0; rr < 2; ++rr)
#pragma unroll
      for (int jg = 0; jg < 2; ++jg)
#pragma unroll
        for (int hM = 0; hM < 2; ++hM)
          acc[rr][jg][hM] = (f32x4){0.f, 0.f, 0.f, 0.f};

#pragma unroll
    for (int m = 0; m < 8; ++m) {
      const int doff = 32 * m + 8 * g;
      const uint4 ua0 = *(const uint4*)(xi + r0 * XPAD + doff);
      const uint4 ua1 = *(const uint4*)(xi + r1 * XPAD + doff);
#pragma unroll
      for (int jg = 0; jg < 2; ++jg) {
        const uint4 uc = *(const uint4*)(xj + (jg * 16 + m16) * XPAD + doff);
        const f16x2 c0 = bc2(uc.x), c1 = bc2(uc.y), c2 = bc2(uc.z), c3 = bc2(uc.w);
#pragma unroll
        for (int rr = 0; rr < 2; ++rr) {
          const uint4 ua = rr ? ua1 : ua0;
          const f16x2 a0 = bc2(ua.x), a1 = bc2(ua.y), a2v = bc2(ua.z), a3 = bc2(ua.w);
          const f16x2 p0 = a0 * c0, p1 = a1 * c1, p2 = a2v * c2, p3 = a3 * c3;
          const uint32_t s0 = __builtin_bit_cast(uint32_t, a0 - c0) & 0x7FFF7FFFu;
          const uint32_t s1 = __builtin_bit_cast(uint32_t, a1 - c1) & 0x7FFF7FFFu;
          const uint32_t s2 = __builtin_bit_cast(uint32_t, a2v - c2) & 0x7FFF7FFFu;
          const uint32_t s3 = __builtin_bit_cast(uint32_t, a3 - c3) & 0x7FFF7FFFu;
          uint4 be, bo;
          be.x = __builtin_bit_cast(uint32_t, p0); be.y = s0;
          be.z = __builtin_bit_cast(uint32_t, p1); be.w = s1;
          bo.x = __builtin_bit_cast(uint32_t, p2); bo.y = s2;
          bo.z = __builtin_bit_cast(uint32_t, p3); bo.w = s3;
          const halfx8 bE = bc8(be), bO = bc8(bo);
          acc[rr][jg][0] = __builtin_amdgcn_mfma_f32_16x16x32_f16(bc8(af[2 * m][0]),     bE, acc[rr][jg][0], 0, 0, 0);
          acc[rr][jg][1] = __builtin_amdgcn_mfma_f32_16x16x32_f16(bc8(af[2 * m][1]),     bE, acc[rr][jg][1], 0, 0, 0);
          acc[rr][jg][0] = __builtin_amdgcn_mfma_f32_16x16x32_f16(bc8(af[2 * m + 1][0]), bO, acc[rr][jg][0], 0, 0, 0);
          acc[rr][jg][1] = __builtin_amdgcn_mfma_f32_16x16x32_f16(bc8(af[2 * m + 1][1]), bO, acc[rr][jg][1], 0, 0, 0);
        }
      }
    }

    // relu+bias+mask, pack: phase-0 -> LDS, phase-1 -> regs
#pragma unroll
    for (int rr = 0; rr < 2; ++rr) {
      const int rloc = rr ? r1 : r0;
      const int gi = hi0 + rloc;
#pragma unroll
      for (int jg = 0; jg < 2; ++jg) {
        const int jl = jg * 16 + m16;
        const int gj = hj0 + jl;
        const float msk = (gi >= 0 && gi < len && gj >= 0 && gj < len) ? 1.f : 0.f;
        {
          const f32x4 a = acc[rr][jg][0];
          uint2 st;
          st.x = pk16(fmaxf(a[0] + b1v[0][0], 0.f) * msk, fmaxf(a[1] + b1v[0][1], 0.f) * msk);
          st.y = pk16(fmaxf(a[2] + b1v[0][2], 0.f) * msk, fmaxf(a[3] + b1v[0][3], 0.f) * msk);
          *(uint2*)(hts + (rloc * HT + jl) * PPH + g * 4) = st;
        }
        {
          const f32x4 a = acc[rr][jg][1];
          uint2 st;
          st.x = pk16(fmaxf(a[0] + b1v[1][0], 0.f) * msk, fmaxf(a[1] + b1v[1][1], 0.f) * msk);
          st.y = pk16(fmaxf(a[2] + b1v[1][2], 0.f) * msk, fmaxf(a[3] + b1v[1][3], 0.f) * msk);
          accH1p[ip * 4 + jg * 2 + rr] = st;
        }
      }
    }
  }
  __syncthreads();

  // ---- conv phase 0 (channels 0..15) ----
  float a2[2][32];
#pragma unroll
  for (int js = 0; js < 2; ++js)
#pragma unroll
    for (int s = 0; s < 32; ++s) a2[js][s] = 0.f;

  {
    uint2 wf[7];
#pragma unroll
    for (int kk = 0; kk < 7; ++kk) wf[kk] = w2b[kk * 64 + lane];
#pragma unroll
    for (int t = 0; t < 8; ++t) {
      const int r = wv + 4 * t;            // halo row 0..31
#pragma unroll
      for (int js = 0; js < 2; ++js) {
        const _Float16* base = hts + (r * HT + js * 16 + m16) * PPH + g * 4;
        f32x4 c = (f32x4){0.f, 0.f, 0.f, 0.f};
#pragma unroll
        for (int kk = 0; kk < 7; ++kk)
          c = __builtin_amdgcn_mfma_f32_16x16x16f16(bc4(wf[kk]), bc4(*(const uint2*)(base + kk * PPH)), c, 0, 0, 0);
#pragma unroll
        for (int reg = 0; reg < 4; ++reg)
          a2[js][4 * t - reg + 3] += c[reg];
      }
    }
  }
  __syncthreads();

  // ---- write h phase-1 halves (channels 16..31) into hts ----
#pragma unroll
  for (int ip = 0; ip < 4; ++ip)
#pragma unroll
    for (int rr = 0; rr < 2; ++rr)
#pragma unroll
      for (int jg = 0; jg < 2; ++jg) {
        const int rloc = wv * 8 + 2 * ip + rr;
        const int jl = jg * 16 + m16;
        *(uint2*)(hts + (rloc * HT + jl) * PPH + g * 4) = accH1p[ip * 4 + jg * 2 + rr];
      }
  __syncthreads();

  // ---- conv phase 1 (channels 16..31) ----
  {
    uint2 wf[7];
#pragma unroll
    for (int kk = 0; kk < 7; ++kk) wf[kk] = w2b[448 + kk * 64 + lane];
#pragma unroll
    for (int t = 0; t < 8; ++t) {
      const int r = wv + 4 * t;
#pragma unroll
      for (int js = 0; js < 2; ++js) {
        const _Float16* base = hts + (r * HT + js * 16 + m16) * PPH + g * 4;
        f32x4 c = (f32x4){0.f, 0.f, 0.f, 0.f};
#pragma unroll
        for (int kk = 0; kk < 7; ++kk)
          c = __builtin_amdgcn_mfma_f32_16x16x16f16(bc4(wf[kk]), bc4(*(const uint2*)(base + kk * PPH)), c, 0, 0, 0);
#pragma unroll
        for (int reg = 0; reg < 4; ++reg)
          a2[js][4 * t - reg + 3] += c[reg];
      }
    }
  }

  // ---- scatter to reduce buffer (aliases dead x staging) ----
  if (g < 2) {
#pragma unroll
    for (int s = 0; s < 32; ++s) {
      rb[wv][g][s][m16]      = a2[0][s];
      rb[wv][g][s][16 + m16] = a2[1][s];
    }
  }
  __syncthreads();

  // ---- reduce + store ----
  for (int p = tid; p < OT * OT; p += 256) {
    const int oi = p / OT, oj = p - (p / OT) * OT;
    float sum = 0.f;
#pragma unroll
    for (int ww = 0; ww < 4; ++ww)
#pragma unroll
      for (int gg = 0; gg < 2; ++gg) {
        const int s = oi - ww + 4 * gg + 3;
        if (s < 32) sum += rb[ww][gg][s][oj];
      }
    const int gi = oi0 + oi, gj = oj0 + oj;
    if (gi < LL && gj < LL)
      out[(size_t)(b * LL + gi) * LL + gj] = (gi < len && gj < len) ? sum + bias : 0.f;
  }
}

extern "C" void kernel_launch(void* const* d_in, const int* in_sizes, int n_in,
                              void* d_out, int out_size, void* d_ws, size_t ws_size,
                              hipStream_t stream) {
  const float* x   = (const float*)d_in[0];
  const int*   pl  = (const int*)d_in[1];
  const float* W1  = (const float*)d_in[2];
  const float* b1  = (const float*)d_in[3];
  const float* W2  = (const float*)d_in[4];
  const float* b2  = (const float*)d_in[5];
  float* out = (float*)d_out;

  _Float16* w1p = (_Float16*)d_ws;                      // 32,768 B
  uint2*    w2b = (uint2*)((char*)d_ws + 32768);        // 7,168 B
  _Float16* xf  = (_Float16*)((char*)d_ws + 65536);     // 1,048,576 B

  bepler_pack<<<dim3(321), dim3(256), 0, stream>>>(x, W1, W2, xf, w1p, w2b);
  dim3 gF(10, 10, 8);  // (j-tile/26, i-tile/26, b) — round-5 proven order
  bepler_fused<<<gF, dim3(256), 0, stream>>>(xf, pl, (const uint4*)w1p, b1, w2b, b2, out);
}